// Round 10
// baseline (1362.062 us; speedup 1.0000x reference)
//
#include <hip/hip_runtime.h>

#define NT    16384
#define DDIM  512
#define HDIM  1365
#define HPAD  1408
#define NEXP  16
#define BK    64
#define BM    128
#define MAXTILES 656
#define MAXSLOTS 83968   // 656 * 128

typedef unsigned short u16;
typedef unsigned int   u32;
typedef __attribute__((ext_vector_type(8))) __bf16 bf16x8;
typedef __attribute__((ext_vector_type(4))) float  f32x4;
typedef __attribute__((address_space(3))) void lds_void;
typedef __attribute__((address_space(1))) void glb_void;

__device__ __forceinline__ u16 f2bf(float f) {
  union { float f; u32 u; } v; v.f = f;
  u32 u = v.u;
  u += 0x7fffu + ((u >> 16) & 1u);
  return (u16)(u >> 16);
}

__device__ __forceinline__ float bf2f(u16 b) {
  union { u32 u; float f; } v; v.u = ((u32)b) << 16;
  return v.f;
}

__device__ __forceinline__ f32x4 mfma16(bf16x8 a, bf16x8 b, f32x4 c) {
  return __builtin_amdgcn_mfma_f32_16x16x32_bf16(a, b, c, 0, 0, 0);
}

__device__ __forceinline__ void gload16(const u16* g, u16* l) {
  __builtin_amdgcn_global_load_lds((const glb_void*)g, (lds_void*)l, 16, 0, 0);
}

// swizzled LDS fragment read: tile is [rows][64] u16, row stride 128B
__device__ __forceinline__ bf16x8 lds_frag(const u16* base, int row, int e0) {
  int b = ((row << 7) + (e0 << 1)) ^ ((row & 7) << 4);
  return *(const bf16x8*)((const char*)base + b);
}

// m204 bijective XCD swizzle for arbitrary n (bid < n):
// XCD x (= bid&7 under round-robin dispatch) gets a CONTIGUOUS work chunk.
__device__ __forceinline__ int swz_n(int bid, int n) {
  int q = n >> 3, r = n & 7;
  int xcd = bid & 7, j = bid >> 3;
  return (xcd < r ? xcd * (q + 1) : r * (q + 1) + (xcd - r) * q) + j;
}

// ---------- batched: w1/w2/sw1/sw2 (D,H) fp32 -> (HPAD,D) bf16, zero-padded ----------
__global__ void transpose12_kernel(const float* __restrict__ w1, const float* __restrict__ w2,
                                   const float* __restrict__ sw1, const float* __restrict__ sw2,
                                   u16* __restrict__ w1t, u16* __restrict__ w2t,
                                   u16* __restrict__ sw1t, u16* __restrict__ sw2t) {
  __shared__ float tile[32][65];
  int z = blockIdx.z;
  const float* in; u16* out;
  if (z < 16)      { in = w1 + (size_t)z * DDIM * HDIM;        out = w1t + (size_t)z * HPAD * DDIM; }
  else if (z < 32) { in = w2 + (size_t)(z - 16) * DDIM * HDIM; out = w2t + (size_t)(z - 16) * HPAD * DDIM; }
  else if (z == 32){ in = sw1; out = sw1t; }
  else             { in = sw2; out = sw2t; }
  int h0 = blockIdx.x * 32, d0 = blockIdx.y * 64;
  int tx = threadIdx.x, ty = threadIdx.y;
  int h = h0 + tx;
#pragma unroll
  for (int r = 0; r < 8; ++r) {
    int d = d0 + ty + r * 8;
    float v = (h < HDIM) ? in[(size_t)d * HDIM + h] : 0.f;
    tile[tx][ty + r * 8] = v;
  }
  __syncthreads();
#pragma unroll
  for (int r = 0; r < 4; ++r) {
    int hh = h0 + ty + r * 8;
    u32 lo = f2bf(tile[ty + r * 8][2 * tx]);
    u32 hi = f2bf(tile[ty + r * 8][2 * tx + 1]);
    ((u32*)&out[(size_t)hh * DDIM + d0])[tx] = lo | (hi << 16);
  }
}

// ---------- batched: w3/sw3 (H,D) fp32 -> (D,HPAD) bf16, zero-padded ----------
__global__ void transpose3_kernel(const float* __restrict__ w3, const float* __restrict__ sw3,
                                  u16* __restrict__ w3t, u16* __restrict__ sw3t) {
  __shared__ float tile[32][65];
  int z = blockIdx.z;
  const float* in = (z < 16) ? (w3 + (size_t)z * HDIM * DDIM) : sw3;
  u16* out = (z < 16) ? (w3t + (size_t)z * DDIM * HPAD) : sw3t;
  int h0 = blockIdx.x * 64, d0 = blockIdx.y * 32;
  int tx = threadIdx.x, ty = threadIdx.y;
  int d = d0 + tx;
#pragma unroll
  for (int r = 0; r < 8; ++r) {
    int h = h0 + ty + r * 8;
    float v = (h < HDIM) ? in[(size_t)h * DDIM + d] : 0.f;
    tile[tx][ty + r * 8] = v;
  }
  __syncthreads();
#pragma unroll
  for (int r = 0; r < 4; ++r) {
    int dd = d0 + ty + r * 8;
    u32 lo = f2bf(tile[ty + r * 8][2 * tx]);
    u32 hi = f2bf(tile[ty + r * 8][2 * tx + 1]);
    ((u32*)&out[(size_t)dd * HPAD + h0])[tx] = lo | (hi << 16);
  }
}

// ------- R1 fused: x->bf16 convert + logits + top-4 + softmax (8 waves/block) -------
__global__ __launch_bounds__(512) void routing_kernel(
    const float* __restrict__ x, const float* __restrict__ gw,
    const float* __restrict__ rbias, u16* __restrict__ x_bf,
    int* __restrict__ top_e, float* __restrict__ top_w) {
  __shared__ float gwp[NEXP * DDIM];   // 32 KiB
  int tid = threadIdx.x;
  for (int i = tid; i < NEXP * DDIM; i += 512) {
    int d = i >> 4, e = i & 15;
    gwp[e * DDIM + ((d & 7) << 6) + (d >> 3)] = gw[i];
  }
  __syncthreads();
  int w = tid >> 6, lane = tid & 63;
  int t = blockIdx.x * 8 + w;
  const float* xr = x + (size_t)t * DDIM + lane * 8;
  float4 xa = ((const float4*)xr)[0], xb = ((const float4*)xr)[1];
  float xv[8] = {xa.x, xa.y, xa.z, xa.w, xb.x, xb.y, xb.z, xb.w};
  u16 r[8];
#pragma unroll
  for (int k = 0; k < 8; ++k) r[k] = f2bf(xv[k]);
  *(uint4*)&x_bf[(size_t)t * DDIM + lane * 8] = *(const uint4*)r;
  float acc[NEXP];
#pragma unroll
  for (int e = 0; e < NEXP; ++e) {
    const float* ge = gwp + e * DDIM + lane;
    float s = 0.f;
#pragma unroll
    for (int k = 0; k < 8; ++k) s += xv[k] * ge[k << 6];
#pragma unroll
    for (int off = 32; off; off >>= 1) s += __shfl_xor(s, off);
    acc[e] = s + rbias[e];
  }
  if (lane == 0) {
    int sel[4]; float sv[4];
    unsigned used = 0;
#pragma unroll
    for (int i = 0; i < 4; ++i) {
      float best = -1e30f; int bi = 0;
#pragma unroll
      for (int e = 0; e < NEXP; ++e) {
        bool ok = !((used >> e) & 1u) && acc[e] > best;
        best = ok ? acc[e] : best;
        bi   = ok ? e : bi;
      }
      used |= 1u << bi; sel[i] = bi; sv[i] = best;
    }
    float m = sv[0];
    float ex[4]; float s = 0.f;
#pragma unroll
    for (int i = 0; i < 4; ++i) { ex[i] = __expf(sv[i] - m); s += ex[i]; }
    float inv = 1.f / s;
#pragma unroll
    for (int i = 0; i < 4; ++i) {
      top_e[t * 4 + i] = sel[i];
      top_w[t * 4 + i] = ex[i] * inv;
    }
  }
}

// ---------------- R2: hierarchical counting + rank ----------------
__global__ __launch_bounds__(1024) void rank_kernel(const int* __restrict__ top_e,
                                                    int* __restrict__ counts,
                                                    int* __restrict__ top_pos) {
  __shared__ int hist[NEXP], base[NEXP];
  int tid = threadIdx.x;
  int t = blockIdx.x * 1024 + tid;
  if (tid < NEXP) hist[tid] = 0;
  __syncthreads();
  int e4[4], r4[4];
#pragma unroll
  for (int i = 0; i < 4; ++i) {
    e4[i] = top_e[t * 4 + i];
    r4[i] = atomicAdd(&hist[e4[i]], 1);
  }
  __syncthreads();
  if (tid < NEXP) base[tid] = atomicAdd(&counts[tid], hist[tid]);
  __syncthreads();
#pragma unroll
  for (int i = 0; i < 4; ++i) top_pos[t * 4 + i] = base[e4[i]] + r4[i];
}

// ---------------- finalize: padded slot offsets + tile descriptors (wave-parallel) ----
__global__ void finalize_kernel(const int* __restrict__ counts, int* __restrict__ slot_off,
                                int* __restrict__ ntiles, int2* __restrict__ desc) {
  __shared__ int s_off[17], s_tb[17], s_nt[17];
  int tid = threadIdx.x;
  if (tid == 0) {
    int off = 0, td = 0;
    for (int e = 0; e < 17; ++e) {
      int c = (e == 16) ? NT : counts[e];
      s_off[e] = off; slot_off[e] = off;
      int nt = (c + BM - 1) / BM;
      s_nt[e] = nt; s_tb[e] = td;
      td += nt; off += nt * BM;
    }
    slot_off[17] = off;
    *ntiles = td;
  }
  __syncthreads();
  for (int e = 0; e < 17; ++e) {
    int nt = s_nt[e], tb = s_tb[e], o = s_off[e];
    for (int i = tid; i < nt; i += 64)
      desc[tb + i] = make_int2(e, o + i * BM);
  }
}

// ---------------- scatter ----------------
__global__ void scatter_kernel(const int* __restrict__ top_e, const float* __restrict__ top_w,
                               const int* __restrict__ top_pos, const int* __restrict__ slot_off,
                               int* __restrict__ tok_pad, float* __restrict__ w_pad,
                               int* __restrict__ pos_list) {
  int t = blockIdx.x * 256 + threadIdx.x;
  if (t >= NT) return;
#pragma unroll
  for (int i = 0; i < 4; ++i) {
    int e = top_e[t * 4 + i];
    int slot = slot_off[e] + top_pos[t * 4 + i];
    tok_pad[slot] = t;
    w_pad[slot] = top_w[t * 4 + i];
    pos_list[t * 4 + i] = slot;
  }
  int sh = slot_off[16] + t;
  tok_pad[sh] = t;
  w_pad[sh] = 1.f;
}

// ---------------- K1: grouped GEMM1 + SwiGLU -> h bf16 (m97-style, 5 blk/CU) --------
__global__ __launch_bounds__(256, 5) void gemm1_kernel(
    const u16* __restrict__ x_bf, const u16* __restrict__ w1t, const u16* __restrict__ w2t,
    const u16* __restrict__ sw1t, const u16* __restrict__ sw2t,
    const int* __restrict__ ntiles, const int2* __restrict__ desc,
    const int* __restrict__ tok_pad, u16* __restrict__ h, int lo, int ntc) {
  int wk = swz_n(blockIdx.x, ntc * 22);
  int tloc = wk / 22, hblk = wk - tloc * 22;
  int ti = (lo >> 7) + tloc;
  if (ti >= *ntiles) return;
  int2 de = desc[ti];
  int e = de.x, m0 = de.y;
  int n0 = hblk * 64;
  const u16* W1 = (e == 16) ? sw1t : (w1t + (size_t)e * HPAD * DDIM);
  const u16* W2 = (e == 16) ? sw2t : (w2t + (size_t)e * HPAD * DDIM);

  __shared__ u16 smem[16384];   // 32 KiB: xs 16K | bs 16K
  u16* xs = smem;
  u16* bs = smem + 8192;

  int tid = threadIdx.x, w = tid >> 6, lane = tid & 63;
  int wm = w >> 1, wn = w & 1, lr = lane & 15, lk = lane >> 4;

  const u16* ags[4]; const u16* bgs[4];
  int ce = (((lane & 7) ^ ((lane >> 3) & 7)) << 3);
#pragma unroll
  for (int p = 0; p < 4; ++p) {
    int r = w * 32 + p * 8 + (lane >> 3);
    ags[p] = x_bf + (size_t)tok_pad[m0 + r] * DDIM + ce;
    int grp = (w * 32 + p * 8) >> 4;                 // uniform per (w,p)
    const u16* Wsrc = (grp & 1) ? W2 : W1;
    int hrow = n0 + ((grp >> 1) << 4) + (r & 15);
    bgs[p] = Wsrc + (size_t)hrow * DDIM + ce;
  }

  f32x4 acc[4][4] = {};

  for (int ks = 0; ks < DDIM / BK; ++ks) {
    int k0 = ks * BK;
#pragma unroll
    for (int p = 0; p < 4; ++p) {
      gload16(ags[p] + k0, xs + ((w * 32 + p * 8) << 6));
      gload16(bgs[p] + k0, bs + ((w * 32 + p * 8) << 6));
    }
    __syncthreads();
#pragma unroll
    for (int kf = 0; kf < 2; ++kf) {
      int e0 = kf * 32 + lk * 8;
      bf16x8 bfr[4];
#pragma unroll
      for (int nf = 0; nf < 4; ++nf)
        bfr[nf] = lds_frag(bs, wn * 64 + nf * 16 + lr, e0);
#pragma unroll
      for (int mf = 0; mf < 4; ++mf) {
        bf16x8 a = lds_frag(xs, wm * 64 + mf * 16 + lr, e0);
#pragma unroll
        for (int nf = 0; nf < 4; ++nf)
          acc[mf][nf] = mfma16(a, bfr[nf], acc[mf][nf]);
      }
    }
    __syncthreads();
  }

  // epilogue: SwiGLU (register-local pairs), XOR-swizzled LDS stage, coalesced copy.
  u16* hs = smem;
#pragma unroll
  for (int mf = 0; mf < 4; ++mf)
#pragma unroll
    for (int nf = 0; nf < 4; nf += 2)
#pragma unroll
      for (int j = 0; j < 4; ++j) {
        float g = acc[mf][nf][j], u = acc[mf][nf + 1][j];
        float hv = g * u / (1.f + __expf(-g));
        int row = wm * 64 + mf * 16 + lk * 4 + j;
        int col = wn * 32 + (nf >> 1) * 16 + lr;
        hs[((row << 6) + col) ^ ((row & 7) << 3)] = f2bf(hv);
      }
  __syncthreads();
#pragma unroll
  for (int i = 0; i < 4; ++i) {
    int idx = (i * 256 + tid) * 8;
    int row = idx >> 6, col = idx & 63;
    *(uint4*)&h[(size_t)(m0 - lo + row) * HPAD + n0 + col] =
        *(uint4*)&hs[idx ^ ((row & 7) << 3)];
  }
}

// ---------------- K2: grouped GEMM2, weighted (m97-style, 5 blk/CU) ----------------
template <bool YMODE>
__global__ __launch_bounds__(256, 5) void gemm2_kernel(
    const u16* __restrict__ h, const u16* __restrict__ w3t, const u16* __restrict__ sw3t,
    const int* __restrict__ ntiles, const int2* __restrict__ desc,
    const int* __restrict__ tok_pad, const float* __restrict__ w_pad,
    u16* __restrict__ y, float* __restrict__ out, int lo, int ntc) {
  int wk = swz_n(blockIdx.x, ntc * 4);
  int tloc = wk >> 2, dblk = wk & 3;
  int ti = (lo >> 7) + tloc;
  if (ti >= *ntiles) return;
  int2 de = desc[ti];
  int e = de.x, m0 = de.y;
  int n0 = dblk * 128;
  const u16* W3 = (e == 16) ? sw3t : (w3t + (size_t)e * DDIM * HPAD);

  __shared__ u16 smem[16384];   // exactly 32 KiB
  u16* hs = smem;
  u16* ws3 = smem + 8192;

  int tid = threadIdx.x, w = tid >> 6, lane = tid & 63;
  int wm = w >> 1, wn = w & 1, lr = lane & 15, lk = lane >> 4;

  const u16* ags[4]; const u16* bgs[4];
  int ce = (((lane & 7) ^ ((lane >> 3) & 7)) << 3);
#pragma unroll
  for (int p = 0; p < 4; ++p) {
    int r = w * 32 + p * 8 + (lane >> 3);
    ags[p] = h + (size_t)(m0 - lo + r) * HPAD + ce;
    bgs[p] = W3 + (size_t)(n0 + r) * HPAD + ce;
  }

  f32x4 acc[4][4] = {};

  for (int ks = 0; ks < HPAD / BK; ++ks) {
    int k0 = ks * BK;
#pragma unroll
    for (int p = 0; p < 4; ++p) {
      gload16(ags[p] + k0, hs + ((w * 32 + p * 8) << 6));
      gload16(bgs[p] + k0, ws3 + ((w * 32 + p * 8) << 6));
    }
    __syncthreads();
#pragma unroll
    for (int kf = 0; kf < 2; ++kf) {
      int e0 = kf * 32 + lk * 8;
      bf16x8 bfr[4];
#pragma unroll
      for (int nf = 0; nf < 4; ++nf)
        bfr[nf] = lds_frag(ws3, wn * 64 + nf * 16 + lr, e0);
#pragma unroll
      for (int mf = 0; mf < 4; ++mf) {
        bf16x8 a = lds_frag(hs, wm * 64 + mf * 16 + lr, e0);
#pragma unroll
        for (int nf = 0; nf < 4; ++nf)
          acc[mf][nf] = mfma16(a, bfr[nf], acc[mf][nf]);
      }
    }
    __syncthreads();
  }

  if constexpr (YMODE) {
    u16* ys = smem;   // [128][128] bf16, XOR-swizzled
#pragma unroll
    for (int mf = 0; mf < 4; ++mf)
#pragma unroll
      for (int j = 0; j < 4; ++j) {
        int row = wm * 64 + mf * 16 + lk * 4 + j;
        float wv = w_pad[m0 + row];
#pragma unroll
        for (int nf = 0; nf < 4; ++nf)
          ys[((row << 7) + wn * 64 + nf * 16 + lr) ^ ((row & 7) << 3)] =
              f2bf(acc[mf][nf][j] * wv);
      }
    __syncthreads();
#pragma unroll
    for (int i = 0; i < 8; ++i) {
      int idx = (i * 256 + tid) * 8;
      int row = idx >> 7, col = idx & 127;
      *(uint4*)&y[(size_t)(m0 + row) * DDIM + n0 + col] =
          *(uint4*)&smem[idx ^ ((row & 7) << 3)];
    }
  } else {
#pragma unroll
    for (int mf = 0; mf < 4; ++mf)
#pragma unroll
      for (int j = 0; j < 4; ++j) {
        int row = wm * 64 + mf * 16 + lk * 4 + j;
        float wv = w_pad[m0 + row];
        float* orow = out + (size_t)tok_pad[m0 + row] * DDIM + n0;
#pragma unroll
        for (int nf = 0; nf < 4; ++nf)
          atomicAdd(&orow[wn * 64 + nf * 16 + lr], acc[mf][nf][j] * wv);
      }
  }
}

// ---------------- reduce: out[t] = y_shared + sum of 4 routed y ----------------
__global__ void reduce_kernel(const u16* __restrict__ y, const int* __restrict__ pos_list,
                              const int* __restrict__ slot_off, float* __restrict__ out) {
  int t = blockIdx.x;
  int c = threadIdx.x;
  int4 pl = ((const int4*)pos_list)[t];
  int sh = slot_off[16] + t;
  ushort4 a = ((const ushort4*)(y + (size_t)sh * DDIM))[c];
  ushort4 b = ((const ushort4*)(y + (size_t)pl.x * DDIM))[c];
  ushort4 d = ((const ushort4*)(y + (size_t)pl.y * DDIM))[c];
  ushort4 e = ((const ushort4*)(y + (size_t)pl.z * DDIM))[c];
  ushort4 f = ((const ushort4*)(y + (size_t)pl.w * DDIM))[c];
  float4 s;
  s.x = bf2f(a.x) + bf2f(b.x) + bf2f(d.x) + bf2f(e.x) + bf2f(f.x);
  s.y = bf2f(a.y) + bf2f(b.y) + bf2f(d.y) + bf2f(e.y) + bf2f(f.y);
  s.z = bf2f(a.z) + bf2f(b.z) + bf2f(d.z) + bf2f(e.z) + bf2f(f.z);
  s.w = bf2f(a.w) + bf2f(b.w) + bf2f(d.w) + bf2f(e.w) + bf2f(f.w);
  ((float4*)(out + (size_t)t * DDIM))[c] = s;
}

extern "C" void kernel_launch(void* const* d_in, const int* in_sizes, int n_in,
                              void* d_out, int out_size, void* d_ws, size_t ws_size,
                              hipStream_t stream) {
  const float* x      = (const float*)d_in[0];
  const float* gate_w = (const float*)d_in[1];
  const float* rbias  = (const float*)d_in[2];
  const float* w1     = (const float*)d_in[3];
  const float* w2     = (const float*)d_in[4];
  const float* w3     = (const float*)d_in[5];
  const float* sw1    = (const float*)d_in[6];
  const float* sw2    = (const float*)d_in[7];
  const float* sw3    = (const float*)d_in[8];
  float* out = (float*)d_out;

  char* ws = (char*)d_ws;
  size_t off = 0;
  auto alloc = [&](size_t bytes) -> char* {
    char* p = ws + off;
    off += (bytes + 255) & ~(size_t)255;
    return p;
  };
  u16* x_bf  = (u16*)alloc((size_t)NT * DDIM * 2);
  u16* w1t   = (u16*)alloc((size_t)NEXP * HPAD * DDIM * 2);
  u16* w2t   = (u16*)alloc((size_t)NEXP * HPAD * DDIM * 2);
  u16* w3t   = (u16*)alloc((size_t)NEXP * DDIM * HPAD * 2);
  u16* sw1t  = (u16*)alloc((size_t)HPAD * DDIM * 2);
  u16* sw2t  = (u16*)alloc((size_t)HPAD * DDIM * 2);
  u16* sw3t  = (u16*)alloc((size_t)DDIM * HPAD * 2);
  int*   counts   = (int*)alloc(64 * 4);
  int*   top_e    = (int*)alloc((size_t)NT * 4 * 4);
  float* top_w    = (float*)alloc((size_t)NT * 4 * 4);
  int*   top_pos  = (int*)alloc((size_t)NT * 4 * 4);
  int*   slot_off = (int*)alloc(32 * 4);
  int*   ntiles   = (int*)alloc(256);
  int2*  desc     = (int2*)alloc((size_t)MAXTILES * 8);
  int*   tok_pad  = (int*)alloc((size_t)MAXSLOTS * 4);
  float* w_pad    = (float*)alloc((size_t)MAXSLOTS * 4);
  int*   pos_list = (int*)alloc((size_t)NT * 4 * 4);
  size_t y_off = off;
  u16* y = (u16*)alloc((size_t)MAXSLOTS * DDIM * 2);
  size_t h_off_y = off;
  (void)in_sizes; (void)n_in; (void)ws_size;

  // ---- adaptive workspace sizing ----
  const size_t per_row = (size_t)HPAD * 2;
  bool ymode;
  size_t h_off, rows_avail;
  size_t avail_y = (ws_size > h_off_y) ? (ws_size - h_off_y) : 0;
  if (avail_y / per_row >= 10496) {
    ymode = true; h_off = h_off_y; rows_avail = avail_y / per_row;
  } else {
    ymode = false; h_off = y_off;
    size_t avail_a = (ws_size > y_off) ? (ws_size - y_off) : 0;
    rows_avail = avail_a / per_row;
  }
  int CS;
  if (rows_avail >= (size_t)MAXSLOTS) CS = MAXSLOTS;
  else {
    CS = (int)((rows_avail / 2048) * 2048);
    if (CS < 2048) CS = (int)((rows_avail / BM) * BM);
    if (CS < BM) CS = BM;
  }
  int NCH = (MAXSLOTS + CS - 1) / CS;
  u16* h = (u16*)(ws + h_off);

  hipMemsetAsync(counts, 0, 64 * 4, stream);
  hipMemsetAsync(tok_pad, 0, (size_t)MAXSLOTS * 4, stream);
  hipMemsetAsync(w_pad, 0, (size_t)MAXSLOTS * 4, stream);
  if (!ymode) hipMemsetAsync(out, 0, (size_t)out_size * 4, stream);

  dim3 tb(32, 8);
  transpose12_kernel<<<dim3(HPAD / 32, DDIM / 64, 34), tb, 0, stream>>>(
      w1, w2, sw1, sw2, w1t, w2t, sw1t, sw2t);
  transpose3_kernel<<<dim3(HPAD / 64, DDIM / 32, 17), tb, 0, stream>>>(
      w3, sw3, w3t, sw3t);

  routing_kernel<<<NT / 8, 512, 0, stream>>>(x, gate_w, rbias, x_bf, top_e, top_w);
  rank_kernel<<<NT / 1024, 1024, 0, stream>>>(top_e, counts, top_pos);
  finalize_kernel<<<1, 64, 0, stream>>>(counts, slot_off, ntiles, desc);
  scatter_kernel<<<NT / 256, 256, 0, stream>>>(top_e, top_w, top_pos, slot_off,
                                               tok_pad, w_pad, pos_list);

  for (int c = 0; c < NCH; ++c) {
    int lo = c * CS;
    int ntc = (MAXSLOTS - lo < CS ? MAXSLOTS - lo : CS) >> 7;   // tiles this chunk
    gemm1_kernel<<<ntc * 22, 256, 0, stream>>>(
        x_bf, w1t, w2t, sw1t, sw2t, ntiles, desc, tok_pad, h, lo, ntc);
    if (ymode)
      gemm2_kernel<true><<<ntc * 4, 256, 0, stream>>>(
          h, w3t, sw3t, ntiles, desc, tok_pad, w_pad, y, out, lo, ntc);
    else
      gemm2_kernel<false><<<ntc * 4, 256, 0, stream>>>(
          h, w3t, sw3t, ntiles, desc, tok_pad, w_pad, y, out, lo, ntc);
  }
  if (ymode) reduce_kernel<<<NT, 128, 0, stream>>>(y, pos_list, slot_off, out);
}

// Round 11
// 585.872 us; speedup vs baseline: 2.3248x; 2.3248x over previous
//
#include <hip/hip_runtime.h>

#define NT    16384
#define DDIM  512
#define HDIM  1365
#define HPAD  1408
#define NEXP  16
#define BK    64
#define BM    128
#define MAXTILES 656
#define MAXSLOTS 83968   // 656 * 128

typedef unsigned short u16;
typedef unsigned int   u32;
typedef __attribute__((ext_vector_type(8))) __bf16 bf16x8;
typedef __attribute__((ext_vector_type(4))) float  f32x4;
typedef __attribute__((address_space(3))) void lds_void;
typedef __attribute__((address_space(1))) void glb_void;

__device__ __forceinline__ u16 f2bf(float f) {
  union { float f; u32 u; } v; v.f = f;
  u32 u = v.u;
  u += 0x7fffu + ((u >> 16) & 1u);
  return (u16)(u >> 16);
}

__device__ __forceinline__ float bf2f(u16 b) {
  union { u32 u; float f; } v; v.u = ((u32)b) << 16;
  return v.f;
}

__device__ __forceinline__ f32x4 mfma16(bf16x8 a, bf16x8 b, f32x4 c) {
  return __builtin_amdgcn_mfma_f32_16x16x32_bf16(a, b, c, 0, 0, 0);
}

__device__ __forceinline__ void gload16(const u16* g, u16* l) {
  __builtin_amdgcn_global_load_lds((const glb_void*)g, (lds_void*)l, 16, 0, 0);
}

// swizzled LDS fragment read: tile is [rows][64] u16, row stride 128B
__device__ __forceinline__ bf16x8 lds_frag(const u16* base, int row, int e0) {
  int b = ((row << 7) + (e0 << 1)) ^ ((row & 7) << 4);
  return *(const bf16x8*)((const char*)base + b);
}

// m204 bijective XCD swizzle for arbitrary n (bid < n):
// XCD x (= bid&7 under round-robin dispatch) gets a CONTIGUOUS work chunk.
__device__ __forceinline__ int swz_n(int bid, int n) {
  int q = n >> 3, r = n & 7;
  int xcd = bid & 7, j = bid >> 3;
  return (xcd < r ? xcd * (q + 1) : r * (q + 1) + (xcd - r) * q) + j;
}

// ---------- batched: w1/w2/sw1/sw2 (D,H) fp32 -> (HPAD,D) bf16, zero-padded ----------
__global__ void transpose12_kernel(const float* __restrict__ w1, const float* __restrict__ w2,
                                   const float* __restrict__ sw1, const float* __restrict__ sw2,
                                   u16* __restrict__ w1t, u16* __restrict__ w2t,
                                   u16* __restrict__ sw1t, u16* __restrict__ sw2t) {
  __shared__ float tile[32][65];
  int z = blockIdx.z;
  const float* in; u16* out;
  if (z < 16)      { in = w1 + (size_t)z * DDIM * HDIM;        out = w1t + (size_t)z * HPAD * DDIM; }
  else if (z < 32) { in = w2 + (size_t)(z - 16) * DDIM * HDIM; out = w2t + (size_t)(z - 16) * HPAD * DDIM; }
  else if (z == 32){ in = sw1; out = sw1t; }
  else             { in = sw2; out = sw2t; }
  int h0 = blockIdx.x * 32, d0 = blockIdx.y * 64;
  int tx = threadIdx.x, ty = threadIdx.y;
  int h = h0 + tx;
#pragma unroll
  for (int r = 0; r < 8; ++r) {
    int d = d0 + ty + r * 8;
    float v = (h < HDIM) ? in[(size_t)d * HDIM + h] : 0.f;
    tile[tx][ty + r * 8] = v;
  }
  __syncthreads();
#pragma unroll
  for (int r = 0; r < 4; ++r) {
    int hh = h0 + ty + r * 8;
    u32 lo = f2bf(tile[ty + r * 8][2 * tx]);
    u32 hi = f2bf(tile[ty + r * 8][2 * tx + 1]);
    ((u32*)&out[(size_t)hh * DDIM + d0])[tx] = lo | (hi << 16);
  }
}

// ---------- batched: w3/sw3 (H,D) fp32 -> (D,HPAD) bf16, zero-padded ----------
__global__ void transpose3_kernel(const float* __restrict__ w3, const float* __restrict__ sw3,
                                  u16* __restrict__ w3t, u16* __restrict__ sw3t) {
  __shared__ float tile[32][65];
  int z = blockIdx.z;
  const float* in = (z < 16) ? (w3 + (size_t)z * HDIM * DDIM) : sw3;
  u16* out = (z < 16) ? (w3t + (size_t)z * DDIM * HPAD) : sw3t;
  int h0 = blockIdx.x * 64, d0 = blockIdx.y * 32;
  int tx = threadIdx.x, ty = threadIdx.y;
  int d = d0 + tx;
#pragma unroll
  for (int r = 0; r < 8; ++r) {
    int h = h0 + ty + r * 8;
    float v = (h < HDIM) ? in[(size_t)h * DDIM + d] : 0.f;
    tile[tx][ty + r * 8] = v;
  }
  __syncthreads();
#pragma unroll
  for (int r = 0; r < 4; ++r) {
    int dd = d0 + ty + r * 8;
    u32 lo = f2bf(tile[ty + r * 8][2 * tx]);
    u32 hi = f2bf(tile[ty + r * 8][2 * tx + 1]);
    ((u32*)&out[(size_t)dd * HPAD + h0])[tx] = lo | (hi << 16);
  }
}

// ------- R1 fused: x->bf16 convert + logits + top-4 + softmax (8 waves/block) -------
__global__ __launch_bounds__(512) void routing_kernel(
    const float* __restrict__ x, const float* __restrict__ gw,
    const float* __restrict__ rbias, u16* __restrict__ x_bf,
    int* __restrict__ top_e, float* __restrict__ top_w) {
  __shared__ float gwp[NEXP * DDIM];   // 32 KiB
  int tid = threadIdx.x;
  for (int i = tid; i < NEXP * DDIM; i += 512) {
    int d = i >> 4, e = i & 15;
    gwp[e * DDIM + ((d & 7) << 6) + (d >> 3)] = gw[i];
  }
  __syncthreads();
  int w = tid >> 6, lane = tid & 63;
  int t = blockIdx.x * 8 + w;
  const float* xr = x + (size_t)t * DDIM + lane * 8;
  float4 xa = ((const float4*)xr)[0], xb = ((const float4*)xr)[1];
  float xv[8] = {xa.x, xa.y, xa.z, xa.w, xb.x, xb.y, xb.z, xb.w};
  u16 r[8];
#pragma unroll
  for (int k = 0; k < 8; ++k) r[k] = f2bf(xv[k]);
  *(uint4*)&x_bf[(size_t)t * DDIM + lane * 8] = *(const uint4*)r;
  float acc[NEXP];
#pragma unroll
  for (int e = 0; e < NEXP; ++e) {
    const float* ge = gwp + e * DDIM + lane;
    float s = 0.f;
#pragma unroll
    for (int k = 0; k < 8; ++k) s += xv[k] * ge[k << 6];
#pragma unroll
    for (int off = 32; off; off >>= 1) s += __shfl_xor(s, off);
    acc[e] = s + rbias[e];
  }
  if (lane == 0) {
    int sel[4]; float sv[4];
    unsigned used = 0;
#pragma unroll
    for (int i = 0; i < 4; ++i) {
      float best = -1e30f; int bi = 0;
#pragma unroll
      for (int e = 0; e < NEXP; ++e) {
        bool ok = !((used >> e) & 1u) && acc[e] > best;
        best = ok ? acc[e] : best;
        bi   = ok ? e : bi;
      }
      used |= 1u << bi; sel[i] = bi; sv[i] = best;
    }
    float m = sv[0];
    float ex[4]; float s = 0.f;
#pragma unroll
    for (int i = 0; i < 4; ++i) { ex[i] = __expf(sv[i] - m); s += ex[i]; }
    float inv = 1.f / s;
#pragma unroll
    for (int i = 0; i < 4; ++i) {
      top_e[t * 4 + i] = sel[i];
      top_w[t * 4 + i] = ex[i] * inv;
    }
  }
}

// ---------------- R2: hierarchical counting + rank ----------------
__global__ __launch_bounds__(1024) void rank_kernel(const int* __restrict__ top_e,
                                                    int* __restrict__ counts,
                                                    int* __restrict__ top_pos) {
  __shared__ int hist[NEXP], base[NEXP];
  int tid = threadIdx.x;
  int t = blockIdx.x * 1024 + tid;
  if (tid < NEXP) hist[tid] = 0;
  __syncthreads();
  int e4[4], r4[4];
#pragma unroll
  for (int i = 0; i < 4; ++i) {
    e4[i] = top_e[t * 4 + i];
    r4[i] = atomicAdd(&hist[e4[i]], 1);
  }
  __syncthreads();
  if (tid < NEXP) base[tid] = atomicAdd(&counts[tid], hist[tid]);
  __syncthreads();
#pragma unroll
  for (int i = 0; i < 4; ++i) top_pos[t * 4 + i] = base[e4[i]] + r4[i];
}

// ---- finish: offsets + desc + pad-tail zero + scatter, one kernel (64 blocks) ----
__global__ __launch_bounds__(256) void finish_kernel(
    const int* __restrict__ counts, const int* __restrict__ top_e,
    const float* __restrict__ top_w, const int* __restrict__ top_pos,
    int* __restrict__ slot_off, int* __restrict__ ntiles, int2* __restrict__ desc,
    int* __restrict__ tok_pad, float* __restrict__ w_pad, int* __restrict__ pos_list) {
  __shared__ int s_off[17], s_tb[17], s_nt[17], s_cnt[17];
  int tid = threadIdx.x;
  if (tid == 0) {
    int off = 0, td = 0;
    for (int e = 0; e < 17; ++e) {
      int c = (e == 16) ? NT : counts[e];
      s_cnt[e] = c; s_off[e] = off;
      int nt = (c + BM - 1) / BM;
      s_nt[e] = nt; s_tb[e] = td;
      td += nt; off += nt * BM;
    }
    if (blockIdx.x == 0) {
      for (int e = 0; e < 17; ++e) slot_off[e] = s_off[e];
      slot_off[17] = off;
      *ntiles = td;
    }
  }
  __syncthreads();
  if (blockIdx.x == 0) {
    for (int e = 0; e < 17; ++e)
      for (int i = tid; i < s_nt[e]; i += 256)
        desc[s_tb[e] + i] = make_int2(e, s_off[e] + i * BM);
  } else if (blockIdx.x == 1) {
    // zero only the per-expert pad tails (rows in [count, nt*BM))
    for (int e = 0; e < 16; ++e) {
      int c = s_cnt[e], padded = s_nt[e] * BM;
      for (int i = c + tid; i < padded; i += 256) {
        tok_pad[s_off[e] + i] = 0;
        w_pad[s_off[e] + i] = 0.f;
      }
    }
  }
  int t = blockIdx.x * 256 + tid;   // grid is exactly NT/256 blocks
#pragma unroll
  for (int i = 0; i < 4; ++i) {
    int e = top_e[t * 4 + i];
    int slot = s_off[e] + top_pos[t * 4 + i];
    tok_pad[slot] = t;
    w_pad[slot] = top_w[t * 4 + i];
    pos_list[t * 4 + i] = slot;
  }
  int sh = s_off[16] + t;
  tok_pad[sh] = t;
  w_pad[sh] = 1.f;
}

// ---------------- K1: grouped GEMM1 + SwiGLU -> h bf16 (m97-style) ----------------
__global__ __launch_bounds__(256, 3) void gemm1_kernel(
    const u16* __restrict__ x_bf, const u16* __restrict__ w1t, const u16* __restrict__ w2t,
    const u16* __restrict__ sw1t, const u16* __restrict__ sw2t,
    const int* __restrict__ ntiles, const int2* __restrict__ desc,
    const int* __restrict__ tok_pad, u16* __restrict__ h, int lo, int ntc) {
  int wk = swz_n(blockIdx.x, ntc * 22);
  int tloc = wk / 22, hblk = wk - tloc * 22;
  int ti = (lo >> 7) + tloc;
  if (ti >= *ntiles) return;
  int2 de = desc[ti];
  int e = de.x, m0 = de.y;
  int n0 = hblk * 64;
  const u16* W1 = (e == 16) ? sw1t : (w1t + (size_t)e * HPAD * DDIM);
  const u16* W2 = (e == 16) ? sw2t : (w2t + (size_t)e * HPAD * DDIM);

  __shared__ u16 smem[16384];   // 32 KiB: xs 16K | bs 16K
  u16* xs = smem;
  u16* bs = smem + 8192;

  int tid = threadIdx.x, w = tid >> 6, lane = tid & 63;
  int wm = w >> 1, wn = w & 1, lr = lane & 15, lk = lane >> 4;

  const u16* ags[4]; const u16* bgs[4];
  int ce = (((lane & 7) ^ ((lane >> 3) & 7)) << 3);
#pragma unroll
  for (int p = 0; p < 4; ++p) {
    int r = w * 32 + p * 8 + (lane >> 3);
    ags[p] = x_bf + (size_t)tok_pad[m0 + r] * DDIM + ce;
    int grp = (w * 32 + p * 8) >> 4;                 // uniform per (w,p)
    const u16* Wsrc = (grp & 1) ? W2 : W1;
    int hrow = n0 + ((grp >> 1) << 4) + (r & 15);
    bgs[p] = Wsrc + (size_t)hrow * DDIM + ce;
  }

  f32x4 acc[4][4] = {};

  for (int ks = 0; ks < DDIM / BK; ++ks) {
    int k0 = ks * BK;
#pragma unroll
    for (int p = 0; p < 4; ++p) {
      gload16(ags[p] + k0, xs + ((w * 32 + p * 8) << 6));
      gload16(bgs[p] + k0, bs + ((w * 32 + p * 8) << 6));
    }
    __syncthreads();
#pragma unroll
    for (int kf = 0; kf < 2; ++kf) {
      int e0 = kf * 32 + lk * 8;
      bf16x8 bfr[4];
#pragma unroll
      for (int nf = 0; nf < 4; ++nf)
        bfr[nf] = lds_frag(bs, wn * 64 + nf * 16 + lr, e0);
#pragma unroll
      for (int mf = 0; mf < 4; ++mf) {
        bf16x8 a = lds_frag(xs, wm * 64 + mf * 16 + lr, e0);
#pragma unroll
        for (int nf = 0; nf < 4; ++nf)
          acc[mf][nf] = mfma16(a, bfr[nf], acc[mf][nf]);
      }
    }
    __syncthreads();
  }

  // epilogue: SwiGLU (register-local pairs), XOR-swizzled LDS stage, coalesced copy.
  u16* hs = smem;
#pragma unroll
  for (int mf = 0; mf < 4; ++mf)
#pragma unroll
    for (int nf = 0; nf < 4; nf += 2)
#pragma unroll
      for (int j = 0; j < 4; ++j) {
        float g = acc[mf][nf][j], u = acc[mf][nf + 1][j];
        float hv = g * u / (1.f + __expf(-g));
        int row = wm * 64 + mf * 16 + lk * 4 + j;
        int col = wn * 32 + (nf >> 1) * 16 + lr;
        hs[((row << 6) + col) ^ ((row & 7) << 3)] = f2bf(hv);
      }
  __syncthreads();
#pragma unroll
  for (int i = 0; i < 4; ++i) {
    int idx = (i * 256 + tid) * 8;
    int row = idx >> 6, col = idx & 63;
    *(uint4*)&h[(size_t)(m0 - lo + row) * HPAD + n0 + col] =
        *(uint4*)&hs[idx ^ ((row & 7) << 3)];
  }
}

// ---------------- K2: grouped GEMM2, weighted (m97-style) ----------------
template <bool YMODE>
__global__ __launch_bounds__(256, 3) void gemm2_kernel(
    const u16* __restrict__ h, const u16* __restrict__ w3t, const u16* __restrict__ sw3t,
    const int* __restrict__ ntiles, const int2* __restrict__ desc,
    const int* __restrict__ tok_pad, const float* __restrict__ w_pad,
    u16* __restrict__ y, float* __restrict__ out, int lo, int ntc) {
  int wk = swz_n(blockIdx.x, ntc * 4);
  int tloc = wk >> 2, dblk = wk & 3;
  int ti = (lo >> 7) + tloc;
  if (ti >= *ntiles) return;
  int2 de = desc[ti];
  int e = de.x, m0 = de.y;
  int n0 = dblk * 128;
  const u16* W3 = (e == 16) ? sw3t : (w3t + (size_t)e * DDIM * HPAD);

  __shared__ u16 smem[16384];   // 32 KiB: hs 16K | ws3 16K; reused as y tile
  __shared__ float swl[BM];
  u16* hs = smem;
  u16* ws3 = smem + 8192;

  int tid = threadIdx.x, w = tid >> 6, lane = tid & 63;
  int wm = w >> 1, wn = w & 1, lr = lane & 15, lk = lane >> 4;

  if (tid < BM) swl[tid] = w_pad[m0 + tid];

  const u16* ags[4]; const u16* bgs[4];
  int ce = (((lane & 7) ^ ((lane >> 3) & 7)) << 3);
#pragma unroll
  for (int p = 0; p < 4; ++p) {
    int r = w * 32 + p * 8 + (lane >> 3);
    ags[p] = h + (size_t)(m0 - lo + r) * HPAD + ce;
    bgs[p] = W3 + (size_t)(n0 + r) * HPAD + ce;
  }

  f32x4 acc[4][4] = {};

  for (int ks = 0; ks < HPAD / BK; ++ks) {
    int k0 = ks * BK;
#pragma unroll
    for (int p = 0; p < 4; ++p) {
      gload16(ags[p] + k0, hs + ((w * 32 + p * 8) << 6));
      gload16(bgs[p] + k0, ws3 + ((w * 32 + p * 8) << 6));
    }
    __syncthreads();
#pragma unroll
    for (int kf = 0; kf < 2; ++kf) {
      int e0 = kf * 32 + lk * 8;
      bf16x8 bfr[4];
#pragma unroll
      for (int nf = 0; nf < 4; ++nf)
        bfr[nf] = lds_frag(ws3, wn * 64 + nf * 16 + lr, e0);
#pragma unroll
      for (int mf = 0; mf < 4; ++mf) {
        bf16x8 a = lds_frag(hs, wm * 64 + mf * 16 + lr, e0);
#pragma unroll
        for (int nf = 0; nf < 4; ++nf)
          acc[mf][nf] = mfma16(a, bfr[nf], acc[mf][nf]);
      }
    }
    __syncthreads();
  }

  if constexpr (YMODE) {
    u16* ys = smem;   // [128][128] bf16, XOR-swizzled
#pragma unroll
    for (int mf = 0; mf < 4; ++mf)
#pragma unroll
      for (int j = 0; j < 4; ++j) {
        int row = wm * 64 + mf * 16 + lk * 4 + j;
        float wv = swl[row];
#pragma unroll
        for (int nf = 0; nf < 4; ++nf)
          ys[((row << 7) + wn * 64 + nf * 16 + lr) ^ ((row & 7) << 3)] =
              f2bf(acc[mf][nf][j] * wv);
      }
    __syncthreads();
#pragma unroll
    for (int i = 0; i < 8; ++i) {
      int idx = (i * 256 + tid) * 8;
      int row = idx >> 7, col = idx & 127;
      *(uint4*)&y[(size_t)(m0 + row) * DDIM + n0 + col] =
          *(uint4*)&smem[idx ^ ((row & 7) << 3)];
    }
  } else {
#pragma unroll
    for (int mf = 0; mf < 4; ++mf)
#pragma unroll
      for (int j = 0; j < 4; ++j) {
        int row = wm * 64 + mf * 16 + lk * 4 + j;
        float wv = swl[row];
        float* orow = out + (size_t)tok_pad[m0 + row] * DDIM + n0;
#pragma unroll
        for (int nf = 0; nf < 4; ++nf)
          atomicAdd(&orow[wn * 64 + nf * 16 + lr], acc[mf][nf][j] * wv);
      }
  }
}

// ---------------- reduce: out[t] = y_shared + sum of 4 routed y ----------------
__global__ void reduce_kernel(const u16* __restrict__ y, const int* __restrict__ pos_list,
                              const int* __restrict__ slot_off, float* __restrict__ out) {
  int t = blockIdx.x;
  int c = threadIdx.x;
  int4 pl = ((const int4*)pos_list)[t];
  int sh = slot_off[16] + t;
  ushort4 a = ((const ushort4*)(y + (size_t)sh * DDIM))[c];
  ushort4 b = ((const ushort4*)(y + (size_t)pl.x * DDIM))[c];
  ushort4 d = ((const ushort4*)(y + (size_t)pl.y * DDIM))[c];
  ushort4 e = ((const ushort4*)(y + (size_t)pl.z * DDIM))[c];
  ushort4 f = ((const ushort4*)(y + (size_t)pl.w * DDIM))[c];
  float4 s;
  s.x = bf2f(a.x) + bf2f(b.x) + bf2f(d.x) + bf2f(e.x) + bf2f(f.x);
  s.y = bf2f(a.y) + bf2f(b.y) + bf2f(d.y) + bf2f(e.y) + bf2f(f.y);
  s.z = bf2f(a.z) + bf2f(b.z) + bf2f(d.z) + bf2f(e.z) + bf2f(f.z);
  s.w = bf2f(a.w) + bf2f(b.w) + bf2f(d.w) + bf2f(e.w) + bf2f(f.w);
  ((float4*)(out + (size_t)t * DDIM))[c] = s;
}

extern "C" void kernel_launch(void* const* d_in, const int* in_sizes, int n_in,
                              void* d_out, int out_size, void* d_ws, size_t ws_size,
                              hipStream_t stream) {
  const float* x      = (const float*)d_in[0];
  const float* gate_w = (const float*)d_in[1];
  const float* rbias  = (const float*)d_in[2];
  const float* w1     = (const float*)d_in[3];
  const float* w2     = (const float*)d_in[4];
  const float* w3     = (const float*)d_in[5];
  const float* sw1    = (const float*)d_in[6];
  const float* sw2    = (const float*)d_in[7];
  const float* sw3    = (const float*)d_in[8];
  float* out = (float*)d_out;

  char* ws = (char*)d_ws;
  size_t off = 0;
  auto alloc = [&](size_t bytes) -> char* {
    char* p = ws + off;
    off += (bytes + 255) & ~(size_t)255;
    return p;
  };
  u16* x_bf  = (u16*)alloc((size_t)NT * DDIM * 2);
  u16* w1t   = (u16*)alloc((size_t)NEXP * HPAD * DDIM * 2);
  u16* w2t   = (u16*)alloc((size_t)NEXP * HPAD * DDIM * 2);
  u16* w3t   = (u16*)alloc((size_t)NEXP * DDIM * HPAD * 2);
  u16* sw1t  = (u16*)alloc((size_t)HPAD * DDIM * 2);
  u16* sw2t  = (u16*)alloc((size_t)HPAD * DDIM * 2);
  u16* sw3t  = (u16*)alloc((size_t)DDIM * HPAD * 2);
  int*   counts   = (int*)alloc(64 * 4);
  int*   top_e    = (int*)alloc((size_t)NT * 4 * 4);
  float* top_w    = (float*)alloc((size_t)NT * 4 * 4);
  int*   top_pos  = (int*)alloc((size_t)NT * 4 * 4);
  int*   slot_off = (int*)alloc(32 * 4);
  int*   ntiles   = (int*)alloc(256);
  int2*  desc     = (int2*)alloc((size_t)MAXTILES * 8);
  int*   tok_pad  = (int*)alloc((size_t)MAXSLOTS * 4);
  float* w_pad    = (float*)alloc((size_t)MAXSLOTS * 4);
  int*   pos_list = (int*)alloc((size_t)NT * 4 * 4);
  size_t y_off = off;
  u16* y = (u16*)alloc((size_t)MAXSLOTS * DDIM * 2);
  size_t h_off_y = off;
  (void)in_sizes; (void)n_in; (void)ws_size;

  // ---- adaptive workspace sizing ----
  const size_t per_row = (size_t)HPAD * 2;
  bool ymode;
  size_t h_off, rows_avail;
  size_t avail_y = (ws_size > h_off_y) ? (ws_size - h_off_y) : 0;
  if (avail_y / per_row >= 10496) {
    ymode = true; h_off = h_off_y; rows_avail = avail_y / per_row;
  } else {
    ymode = false; h_off = y_off;
    size_t avail_a = (ws_size > y_off) ? (ws_size - y_off) : 0;
    rows_avail = avail_a / per_row;
  }
  int CS;
  if (rows_avail >= (size_t)MAXSLOTS) CS = MAXSLOTS;
  else {
    CS = (int)((rows_avail / 2048) * 2048);
    if (CS < 2048) CS = (int)((rows_avail / BM) * BM);
    if (CS < BM) CS = BM;
  }
  int NCH = (MAXSLOTS + CS - 1) / CS;
  u16* h = (u16*)(ws + h_off);

  hipMemsetAsync(counts, 0, 64 * 4, stream);
  if (!ymode) hipMemsetAsync(out, 0, (size_t)out_size * 4, stream);

  dim3 tb(32, 8);
  transpose12_kernel<<<dim3(HPAD / 32, DDIM / 64, 34), tb, 0, stream>>>(
      w1, w2, sw1, sw2, w1t, w2t, sw1t, sw2t);
  transpose3_kernel<<<dim3(HPAD / 64, DDIM / 32, 17), tb, 0, stream>>>(
      w3, sw3, w3t, sw3t);

  routing_kernel<<<NT / 8, 512, 0, stream>>>(x, gate_w, rbias, x_bf, top_e, top_w);
  rank_kernel<<<NT / 1024, 1024, 0, stream>>>(top_e, counts, top_pos);
  finish_kernel<<<NT / 256, 256, 0, stream>>>(counts, top_e, top_w, top_pos,
                                              slot_off, ntiles, desc,
                                              tok_pad, w_pad, pos_list);

  for (int c = 0; c < NCH; ++c) {
    int lo = c * CS;
    int ntc = (MAXSLOTS - lo < CS ? MAXSLOTS - lo : CS) >> 7;   // tiles this chunk
    gemm1_kernel<<<ntc * 22, 256, 0, stream>>>(
        x_bf, w1t, w2t, sw1t, sw2t, ntiles, desc, tok_pad, h, lo, ntc);
    if (ymode)
      gemm2_kernel<true><<<ntc * 4, 256, 0, stream>>>(
          h, w3t, sw3t, ntiles, desc, tok_pad, w_pad, y, out, lo, ntc);
    else
      gemm2_kernel<false><<<ntc * 4, 256, 0, stream>>>(
          h, w3t, sw3t, ntiles, desc, tok_pad, w_pad, y, out, lo, ntc);
  }
  if (ymode) reduce_kernel<<<NT, 128, 0, stream>>>(y, pos_list, slot_off, out);
}